// Round 6
// baseline (207.893 us; speedup 1.0000x reference)
//
#include <hip/hip_runtime.h>
#include <stdint.h>

static const int kN = 50000;
static const int kD = 64;
static const int kE = 800000;
static const int kChunk = 3200;        // edges per binA block
static const int kG = kE / kChunk;     // 250 chunks (exact)
static const int kB = 196;             // buckets = node>>8 (256 nodes/bucket)
static const int kCapB = 6144;         // binB LDS edge cap (48KB)
static const int kHalf = 25000;        // src-half threshold
static const int kInitBlocks = (kN * kD / 4 + 319) / 320;  // 625

#define TFR(x0, x1, r)                                    \
  {                                                       \
    x0 += x1;                                             \
    x1 = ((x1 << (r)) | (x1 >> (32 - (r))));              \
    x1 ^= x0;                                             \
  }

// Threefry-2x32, 20 rounds, JAX key schedule (partitionable mode verified R1).
__host__ __device__ inline void tf2x32(uint32_t k0, uint32_t k1, uint32_t x0,
                                       uint32_t x1, uint32_t* o0, uint32_t* o1) {
  uint32_t k2 = k0 ^ k1 ^ 0x1BD11BDAu;
  x0 += k0; x1 += k1;
  TFR(x0, x1, 13) TFR(x0, x1, 15) TFR(x0, x1, 26) TFR(x0, x1, 6)
  x0 += k1; x1 += k2 + 1u;
  TFR(x0, x1, 17) TFR(x0, x1, 29) TFR(x0, x1, 16) TFR(x0, x1, 24)
  x0 += k2; x1 += k0 + 2u;
  TFR(x0, x1, 13) TFR(x0, x1, 15) TFR(x0, x1, 26) TFR(x0, x1, 6)
  x0 += k0; x1 += k1 + 3u;
  TFR(x0, x1, 17) TFR(x0, x1, 29) TFR(x0, x1, 16) TFR(x0, x1, 24)
  x0 += k1; x1 += k2 + 4u;
  TFR(x0, x1, 13) TFR(x0, x1, 15) TFR(x0, x1, 26) TFR(x0, x1, 6)
  x0 += k2; x1 += k0 + 5u;
  *o0 = x0; *o1 = x1;
}

__device__ inline float jax_dropout(float h, uint32_t k0, uint32_t k1, uint32_t idx) {
  uint32_t a, b;
  tf2x32(k0, k1, 0u, idx, &a, &b);
  uint32_t bits = a ^ b;
  float u = __uint_as_float((bits >> 9) | 0x3f800000u) - 1.0f;
  return (u < 0.9f) ? (h / 0.9f) : 0.0f;
}

__device__ inline unsigned short f2bf(float v) {  // RNE f32->bf16
  uint32_t x = __float_as_uint(v);
  return (unsigned short)((x + 0x7fffu + ((x >> 16) & 1u)) >> 16);
}
__device__ inline float bf2f(unsigned short b) {
  return __uint_as_float(((uint32_t)b) << 16);
}

// ---------------- fused: binA (blocks < kG) + init (rest) ----------------
__global__ __launch_bounds__(320) void fusedA_k(
    const int* __restrict__ esrc, const int* __restrict__ edst,
    const float* __restrict__ evals, int* __restrict__ locOffT,
    int2* __restrict__ staged, const int* __restrict__ x,
    const float* __restrict__ w, float* __restrict__ acc,
    unsigned short* __restrict__ hB, uint32_t k0, uint32_t k1) {
  int t = threadIdx.x;
  if (blockIdx.x < kG) {
    // ---- binA: per-chunk LDS sort by bucket, coalesced staging ----
    __shared__ int2 buf[kChunk];
    __shared__ int hist[kB];
    __shared__ int off[kB + 1];
    __shared__ int sm[2][256];
    int c = blockIdx.x;
    int base = c * kChunk;
    for (int i = t; i < kB; i += 320) hist[i] = 0;
    __syncthreads();
    int2 sv[10];
    int bkt[10];
#pragma unroll
    for (int i = 0; i < 10; ++i) {
      int e = base + t + i * 320;
      int d = edst[e];
      int b = d >> 8;
      bkt[i] = b;
      sv[i] = make_int2(((d & 255) << 16) | esrc[e], __float_as_int(evals[e]));
      atomicAdd(&hist[b], 1);
    }
    __syncthreads();
    int v = 0;
    if (t < 256) {
      v = (t < kB) ? hist[t] : 0;
      sm[0][t] = v;
    }
    __syncthreads();
    int p = 0;
    for (int o = 1; o < 256; o <<= 1) {
      if (t < 256) sm[p ^ 1][t] = sm[p][t] + ((t >= o) ? sm[p][t - o] : 0);
      __syncthreads();
      p ^= 1;
    }
    if (t < kB) off[t] = sm[p][t] - v;
    if (t == 0) off[kB] = kChunk;
    __syncthreads();
    for (int i = t; i <= kB; i += 320) locOffT[i * kG + c] = off[i];
    for (int i = t; i < kB; i += 320) hist[i] = off[i];  // cursors
    __syncthreads();
#pragma unroll
    for (int i = 0; i < 10; ++i) {
      int pos = atomicAdd(&hist[bkt[i]], 1);  // LDS atomic
      buf[pos] = sv[i];
    }
    __syncthreads();
    for (int i = t; i < kChunk; i += 320) staged[base + i] = buf[i];
  } else {
    // ---- init: acc = h0 (f32), hB = bf16(dropout(h0, dk1)) ----
    int gi = (blockIdx.x - kG) * 320 + t;  // one float4 per thread
    if (gi >= kN * kD / 4) return;
    int n = gi >> 4, d4 = gi & 15;
    float4 v = reinterpret_cast<const float4*>(w)[(size_t)x[n] * 16 + d4];
    reinterpret_cast<float4*>(acc)[gi] = v;
    uint32_t idx = (uint32_t)gi * 4u;
    ushort4 o;
    o.x = f2bf(jax_dropout(v.x, k0, k1, idx + 0));
    o.y = f2bf(jax_dropout(v.y, k0, k1, idx + 1));
    o.z = f2bf(jax_dropout(v.z, k0, k1, idx + 2));
    o.w = f2bf(jax_dropout(v.w, k0, k1, idx + 3));
    reinterpret_cast<ushort4*>(hB)[gi] = o;
  }
}

// Column totals + exclusive scan of bucket sizes (merged scanM+scanBB).
__global__ __launch_bounds__(256) void scanAll_k(const int* __restrict__ locOffT,
                                                 int* __restrict__ bucketBase,
                                                 int* __restrict__ offsets) {
  __shared__ int sm[2][256];
  int t = threadIdx.x;
  int tot = 0;
  if (t < kB) {
    const int* r0 = locOffT + t * kG;
    const int* r1 = locOffT + (t + 1) * kG;
    for (int c = 0; c < kG; ++c) tot += r1[c] - r0[c];
  }
  sm[0][t] = tot;
  __syncthreads();
  int p = 0;
  for (int o = 1; o < 256; o <<= 1) {
    sm[p ^ 1][t] = sm[p][t] + ((t >= o) ? sm[p][t - o] : 0);
    __syncthreads();
    p ^= 1;
  }
  if (t < kB) bucketBase[t] = sm[p][t] - tot;
  if (t == 0) {
    bucketBase[kB] = kE;
    offsets[kN] = kE;  // sentinel
  }
}

// Pass B: one block per bucket; split each node's list by src-half.
// 512 LDS counters keyed (dloc*2 + half); writes offsets[] and mid[].
__global__ __launch_bounds__(256) void binB_k(const int2* __restrict__ staged,
                                              const int* __restrict__ locOffT,
                                              const int* __restrict__ bucketBase,
                                              int2* __restrict__ csr_sv,
                                              int* __restrict__ offsets,
                                              int* __restrict__ mid) {
  __shared__ int2 buf[kCapB];
  __shared__ int sm[2][256];
  __shared__ int cnt[512];  // (dloc*2+half) count -> cursor
  int b = blockIdx.x, t = threadIdx.x;
  int base = bucketBase[b];
  int size = bucketBase[b + 1] - base;
  if (size > kCapB) size = kCapB;  // defensive
  int myOff = 0, myCnt = 0;
  if (t < kG) {
    myOff = locOffT[b * kG + t];
    myCnt = locOffT[(b + 1) * kG + t] - myOff;
  }
  sm[0][t] = myCnt;
  __syncthreads();
  int p = 0;
  for (int o = 1; o < 256; o <<= 1) {
    sm[p ^ 1][t] = sm[p][t] + ((t >= o) ? sm[p][t - o] : 0);
    __syncthreads();
    p ^= 1;
  }
  int myPos = sm[p][t] - myCnt;
  for (int i = 0; i < myCnt; ++i) {
    int q = myPos + i;
    if (q < kCapB) buf[q] = staged[t * kChunk + myOff + i];
  }
  cnt[t] = 0;
  cnt[t + 256] = 0;
  __syncthreads();
  for (int i = t; i < size; i += 256) {
    int2 e = buf[i];
    int key = ((e.x >> 16) << 1) | (((e.x & 0xffff) >= kHalf) ? 1 : 0);
    atomicAdd(&cnt[key], 1);
  }
  __syncthreads();
  int a0 = cnt[2 * t], a1 = cnt[2 * t + 1];
  int s = a0 + a1;
  sm[0][t] = s;
  __syncthreads();
  p = 0;
  for (int o = 1; o < 256; o <<= 1) {
    sm[p ^ 1][t] = sm[p][t] + ((t >= o) ? sm[p][t - o] : 0);
    __syncthreads();
    p ^= 1;
  }
  int basePair = sm[p][t] - s;
  int node = (b << 8) + t;
  if (node < kN) {
    offsets[node] = base + basePair;
    mid[node] = base + basePair + a0;
  }
  cnt[2 * t] = basePair;
  cnt[2 * t + 1] = basePair + a0;  // cursors
  __syncthreads();
  for (int i = t; i < size; i += 256) {
    int2 e = buf[i];
    int s16 = e.x & 0xffff;
    int key = ((e.x >> 16) << 1) | ((s16 >= kHalf) ? 1 : 0);
    int pp = atomicAdd(&cnt[key], 1);  // LDS atomic
    csr_sv[base + pp] = make_int2(s16, e.y);
  }
}

// Half-pass SpMM: one wave per node, lane = dim; edges in [lo[n], hi[n]).
// phase 0: partial = sum. phase 1: total = partial + sum; epilogue.
// First 512 blocks stream-prefetch the active 3.2MB src-half into their
// XCD's L2 (blockIdx%8 = XCD round-robin); non-gather traffic nontemporal.
__global__ __launch_bounds__(256) void layerH_k(
    const int2* __restrict__ csr_sv, const int* __restrict__ lo,
    const int* __restrict__ hi, const unsigned short* __restrict__ hIn,
    float* __restrict__ partial, float* __restrict__ acc,
    unsigned short* __restrict__ hOut, uint32_t k0, uint32_t k1,
    int phase, int last) {
  if (blockIdx.x < 512) {  // 64 slices x 8 XCDs
    const uint4* pf = reinterpret_cast<const uint4*>(hIn + (size_t)phase * kHalf * kD);
    int slice = blockIdx.x >> 3;
    for (int i = threadIdx.x; i < 3125; i += 256) {
      uint4 v = pf[slice * 3125 + i];
      asm volatile("" ::"v"(v.x), "v"(v.y), "v"(v.z), "v"(v.w));
    }
  }
  int gtid = blockIdx.x * blockDim.x + threadIdx.x;
  int node = gtid >> 6;
  int lane = threadIdx.x & 63;
  if (node >= kN) return;
  int beg = __builtin_amdgcn_readfirstlane(lo[node]);
  int end = __builtin_amdgcn_readfirstlane(hi[node]);
  float sum = 0.0f;
  for (int c = beg; c < end; c += 8) {
    const int2* p = csr_sv + c;  // wave-uniform -> scalar loads
    int rem = end - c;
    float g[8], vv[8];
#pragma unroll
    for (int j = 0; j < 8; ++j) {
      int2 sv = p[j];  // over-read stays in allocated ws; predicated off
      int s = (j < rem) ? sv.x : 0;
      vv[j] = (j < rem) ? __int_as_float(sv.y) : 0.0f;
      g[j] = bf2f(hIn[(s << 6) + lane]);  // coalesced 128B row gather
    }
#pragma unroll
    for (int j = 0; j < 8; ++j) sum += vv[j] * g[j];
  }
  int idx = (node << 6) + lane;
  if (phase == 0) {
    __builtin_nontemporal_store(sum, &partial[idx]);
  } else {
    sum += __builtin_nontemporal_load(&partial[idx]);
    float a = __builtin_nontemporal_load(&acc[idx]);
    if (last) {
      __builtin_nontemporal_store((a + sum) * 0.25f, &acc[idx]);
    } else {
      __builtin_nontemporal_store(a + sum, &acc[idx]);
      __builtin_nontemporal_store(f2bf(jax_dropout(sum, k0, k1, (uint32_t)idx)),
                                  &hOut[idx]);
    }
  }
}

extern "C" void kernel_launch(void* const* d_in, const int* in_sizes, int n_in,
                              void* d_out, int out_size, void* d_ws, size_t ws_size,
                              hipStream_t stream) {
  const int* x = (const int*)d_in[0];
  const int* esrc = (const int*)d_in[1];
  const int* edst = (const int*)d_in[2];
  const float* evals = (const float*)d_in[3];
  const float* w = (const float*)d_in[4];
  float* acc = (float*)d_out;

  // ---- workspace layout (~40 MB) ----
  size_t nd = (size_t)kN * kD;
  int2* staged = (int2*)d_ws;                          // kE
  int2* csr_sv = staged + kE;                          // kE (+16 over-read slack)
  unsigned short* hB0 = (unsigned short*)(csr_sv + kE + 16);
  unsigned short* hB1 = hB0 + nd;
  float* partial = (float*)(hB1 + nd);                 // nd f32
  int* locOffT = (int*)(partial + nd);                 // (kB+1)*kG
  int* bucketBase = locOffT + (kB + 1) * kG;           // kB+1
  int* offsets = bucketBase + kB + 1;                  // kN+1
  int* mid = offsets + kN + 1;                         // kN

  // JAX key derivation: key(1)=(0,1) -> split 3 (partitionable, verified R1).
  uint32_t dk[3][2];
  for (int i = 0; i < 3; ++i) tf2x32(0u, 1u, 0u, (uint32_t)i, &dk[i][0], &dk[i][1]);

  // 1) binA + init fused (independent work, fills the whole GPU)
  fusedA_k<<<kG + kInitBlocks, 320, 0, stream>>>(esrc, edst, evals, locOffT, staged,
                                                 x, w, acc, hB0, dk[0][0], dk[0][1]);
  // 2) bucket size scan
  scanAll_k<<<1, 256, 0, stream>>>(locOffT, bucketBase, offsets);
  // 3) final CSR with per-node src-half split
  binB_k<<<kB, 256, 0, stream>>>(staged, locOffT, bucketBase, csr_sv, offsets, mid);

  // 4) 3 layers x 2 src-half phases (gather region 3.2MB -> XCD-L2 resident)
  const int gridL = (kN * kD) / 256;  // 12500 blocks, 4 nodes each
  layerH_k<<<gridL, 256, 0, stream>>>(csr_sv, offsets, mid, hB0, partial, acc, hB1,
                                      dk[1][0], dk[1][1], 0, 0);
  layerH_k<<<gridL, 256, 0, stream>>>(csr_sv, mid, offsets + 1, hB0, partial, acc, hB1,
                                      dk[1][0], dk[1][1], 1, 0);
  layerH_k<<<gridL, 256, 0, stream>>>(csr_sv, offsets, mid, hB1, partial, acc, hB0,
                                      dk[2][0], dk[2][1], 0, 0);
  layerH_k<<<gridL, 256, 0, stream>>>(csr_sv, mid, offsets + 1, hB1, partial, acc, hB0,
                                      dk[2][0], dk[2][1], 1, 0);
  layerH_k<<<gridL, 256, 0, stream>>>(csr_sv, offsets, mid, hB0, partial, acc, hB1,
                                      0u, 0u, 0, 1);
  layerH_k<<<gridL, 256, 0, stream>>>(csr_sv, mid, offsets + 1, hB0, partial, acc, hB1,
                                      0u, 0u, 1, 1);
}

// Round 8
// 160.585 us; speedup vs baseline: 1.2946x; 1.2946x over previous
//
#include <hip/hip_runtime.h>
#include <stdint.h>

static const int kN = 50000;
static const int kD = 64;
static const int kE = 800000;
static const int kChunk = 3200;        // edges per binA block
static const int kG = kE / kChunk;     // 250 chunks (exact)
static const int kB = 196;             // buckets = node>>8 (256 nodes/bucket)
static const int kCapB = 6144;         // binB LDS edge cap (48KB)
static const int kInitBlocks = (kN * kD / 4 + 319) / 320;  // 2500

#define TFR(x0, x1, r)                                    \
  {                                                       \
    x0 += x1;                                             \
    x1 = ((x1 << (r)) | (x1 >> (32 - (r))));              \
    x1 ^= x0;                                             \
  }

// Threefry-2x32, 20 rounds, JAX key schedule (partitionable mode verified R1).
__host__ __device__ inline void tf2x32(uint32_t k0, uint32_t k1, uint32_t x0,
                                       uint32_t x1, uint32_t* o0, uint32_t* o1) {
  uint32_t k2 = k0 ^ k1 ^ 0x1BD11BDAu;
  x0 += k0; x1 += k1;
  TFR(x0, x1, 13) TFR(x0, x1, 15) TFR(x0, x1, 26) TFR(x0, x1, 6)
  x0 += k1; x1 += k2 + 1u;
  TFR(x0, x1, 17) TFR(x0, x1, 29) TFR(x0, x1, 16) TFR(x0, x1, 24)
  x0 += k2; x1 += k0 + 2u;
  TFR(x0, x1, 13) TFR(x0, x1, 15) TFR(x0, x1, 26) TFR(x0, x1, 6)
  x0 += k0; x1 += k1 + 3u;
  TFR(x0, x1, 17) TFR(x0, x1, 29) TFR(x0, x1, 16) TFR(x0, x1, 24)
  x0 += k1; x1 += k2 + 4u;
  TFR(x0, x1, 13) TFR(x0, x1, 15) TFR(x0, x1, 26) TFR(x0, x1, 6)
  x0 += k2; x1 += k0 + 5u;
  *o0 = x0; *o1 = x1;
}

__device__ inline float jax_dropout(float h, uint32_t k0, uint32_t k1, uint32_t idx) {
  uint32_t a, b;
  tf2x32(k0, k1, 0u, idx, &a, &b);
  uint32_t bits = a ^ b;
  float u = __uint_as_float((bits >> 9) | 0x3f800000u) - 1.0f;
  return (u < 0.9f) ? (h / 0.9f) : 0.0f;
}

__device__ inline unsigned short f2bf(float v) {  // RNE f32->bf16
  uint32_t x = __float_as_uint(v);
  return (unsigned short)((x + 0x7fffu + ((x >> 16) & 1u)) >> 16);
}
__device__ inline float bf2f(unsigned short b) {
  return __uint_as_float(((uint32_t)b) << 16);
}

// ------- fused: binA (LDS radix pass A) + init (embed + dropout) -------
__global__ __launch_bounds__(320) void fusedA_k(
    const int* __restrict__ esrc, const int* __restrict__ edst,
    const float* __restrict__ evals, int* __restrict__ locOffT,
    int2* __restrict__ staged, const int* __restrict__ x,
    const float* __restrict__ w, float* __restrict__ acc,
    unsigned short* __restrict__ hB, uint32_t k0, uint32_t k1) {
  int t = threadIdx.x;
  if (blockIdx.x < kG) {
    // ---- binA: per-chunk LDS sort by bucket, coalesced staging ----
    __shared__ int2 buf[kChunk];
    __shared__ int hist[kB];
    __shared__ int off[kB + 1];
    __shared__ int sm[2][256];
    int c = blockIdx.x;
    int base = c * kChunk;
    for (int i = t; i < kB; i += 320) hist[i] = 0;
    __syncthreads();
    int2 sv[10];
    int bkt[10];
#pragma unroll
    for (int i = 0; i < 10; ++i) {
      int e = base + t + i * 320;
      int d = edst[e];
      int b = d >> 8;
      bkt[i] = b;
      sv[i] = make_int2(((d & 255) << 16) | esrc[e], __float_as_int(evals[e]));
      atomicAdd(&hist[b], 1);
    }
    __syncthreads();
    int v = 0;
    if (t < 256) {
      v = (t < kB) ? hist[t] : 0;
      sm[0][t] = v;
    }
    __syncthreads();
    int p = 0;
    for (int o = 1; o < 256; o <<= 1) {
      if (t < 256) sm[p ^ 1][t] = sm[p][t] + ((t >= o) ? sm[p][t - o] : 0);
      __syncthreads();
      p ^= 1;
    }
    if (t < kB) off[t] = sm[p][t] - v;
    if (t == 0) off[kB] = kChunk;
    __syncthreads();
    for (int i = t; i <= kB; i += 320) locOffT[i * kG + c] = off[i];
    for (int i = t; i < kB; i += 320) hist[i] = off[i];  // cursors
    __syncthreads();
#pragma unroll
    for (int i = 0; i < 10; ++i) {
      int pos = atomicAdd(&hist[bkt[i]], 1);  // LDS atomic
      buf[pos] = sv[i];
    }
    __syncthreads();
    for (int i = t; i < kChunk; i += 320) staged[base + i] = buf[i];
  } else {
    // ---- init: acc = h0 (f32), hB = bf16(dropout(h0, dk1)) ----
    int gi = (blockIdx.x - kG) * 320 + t;  // one float4 per thread
    if (gi >= kN * kD / 4) return;
    int n = gi >> 4, d4 = gi & 15;
    float4 v = reinterpret_cast<const float4*>(w)[(size_t)x[n] * 16 + d4];
    reinterpret_cast<float4*>(acc)[gi] = v;
    uint32_t idx = (uint32_t)gi * 4u;
    ushort4 o;
    o.x = f2bf(jax_dropout(v.x, k0, k1, idx + 0));
    o.y = f2bf(jax_dropout(v.y, k0, k1, idx + 1));
    o.z = f2bf(jax_dropout(v.z, k0, k1, idx + 2));
    o.w = f2bf(jax_dropout(v.w, k0, k1, idx + 3));
    reinterpret_cast<ushort4*>(hB)[gi] = o;
  }
}

// Column totals + exclusive scan of bucket sizes (proven R6).
__global__ __launch_bounds__(256) void scanAll_k(const int* __restrict__ locOffT,
                                                 int* __restrict__ bucketBase,
                                                 int* __restrict__ offsets) {
  __shared__ int sm[2][256];
  int t = threadIdx.x;
  int tot = 0;
  if (t < kB) {
    const int* r0 = locOffT + t * kG;
    const int* r1 = locOffT + (t + 1) * kG;
    for (int c = 0; c < kG; ++c) tot += r1[c] - r0[c];
  }
  sm[0][t] = tot;
  __syncthreads();
  int p = 0;
  for (int o = 1; o < 256; o <<= 1) {
    sm[p ^ 1][t] = sm[p][t] + ((t >= o) ? sm[p][t - o] : 0);
    __syncthreads();
    p ^= 1;
  }
  if (t < kB) bucketBase[t] = sm[p][t] - tot;
  if (t == 0) {
    bucketBase[kB] = kE;
    offsets[kN] = kE;  // sentinel
  }
}

// Pass B (proven R5): one block per bucket; gather segments into LDS at known
// positions, node-histogram + scan -> offsets; LDS-cursor scatter to final CSR.
__global__ __launch_bounds__(256) void binB_k(const int2* __restrict__ staged,
                                              const int* __restrict__ locOffT,
                                              const int* __restrict__ bucketBase,
                                              int2* __restrict__ csr_sv,
                                              int* __restrict__ offsets) {
  __shared__ int2 buf[kCapB];
  __shared__ int sm[2][256];
  __shared__ int nodeA[256];  // cnt -> cursor
  int b = blockIdx.x, t = threadIdx.x;
  int base = bucketBase[b];
  int size = bucketBase[b + 1] - base;
  if (size > kCapB) size = kCapB;  // defensive (never hit for this graph)
  int myOff = 0, myCnt = 0;
  if (t < kG) {
    myOff = locOffT[b * kG + t];
    myCnt = locOffT[(b + 1) * kG + t] - myOff;
  }
  sm[0][t] = myCnt;
  __syncthreads();
  int p = 0;
  for (int o = 1; o < 256; o <<= 1) {
    sm[p ^ 1][t] = sm[p][t] + ((t >= o) ? sm[p][t - o] : 0);
    __syncthreads();
    p ^= 1;
  }
  int myPos = sm[p][t] - myCnt;  // chunk-major position within bucket
  for (int i = 0; i < myCnt; ++i) {
    int q = myPos + i;
    if (q < kCapB) buf[q] = staged[t * kChunk + myOff + i];
  }
  nodeA[t] = 0;
  __syncthreads();
  for (int i = t; i < size; i += 256) atomicAdd(&nodeA[buf[i].x >> 16], 1);
  __syncthreads();
  int nc = nodeA[t];
  sm[0][t] = nc;
  __syncthreads();
  p = 0;
  for (int o = 1; o < 256; o <<= 1) {
    sm[p ^ 1][t] = sm[p][t] + ((t >= o) ? sm[p][t - o] : 0);
    __syncthreads();
    p ^= 1;
  }
  int nOff = sm[p][t] - nc;
  int node = (b << 8) + t;
  if (node < kN) offsets[node] = base + nOff;
  nodeA[t] = nOff;  // becomes cursor
  __syncthreads();
  for (int i = t; i < size; i += 256) {
    int2 e = buf[i];
    int dl = e.x >> 16;
    int pp = atomicAdd(&nodeA[dl], 1);  // LDS atomic
    csr_sv[base + pp] = make_int2(e.x & 0xffff, e.y);
  }
}

// One wave per dst node; lane = dim. bf16 gathers (128B row = 1 line), f32
// accumulate; 16 gathers in flight to keep the L2 miss queue full. acc/hOut
// traffic nontemporal to keep L2 for the gather table.
__global__ __launch_bounds__(256) void layer_k(
    const int2* __restrict__ csr_sv, const int* __restrict__ offsets,
    const unsigned short* __restrict__ hIn, float* __restrict__ acc,
    unsigned short* __restrict__ hOut, uint32_t k0, uint32_t k1, int last) {
  int gtid = blockIdx.x * blockDim.x + threadIdx.x;
  int node = gtid >> 6;
  int lane = threadIdx.x & 63;
  if (node >= kN) return;
  int beg = __builtin_amdgcn_readfirstlane(offsets[node]);
  int end = __builtin_amdgcn_readfirstlane(offsets[node + 1]);
  int deg = end - beg;
  float sum = 0.0f;
  for (int c = 0; c < deg; c += 16) {
    const int2* p = csr_sv + beg + c;  // wave-uniform address -> scalar loads
    int rem = deg - c;
    float g[16], vv[16];
#pragma unroll
    for (int j = 0; j < 16; ++j) {
      int2 sv = p[j];  // over-read stays inside allocated ws; predicated off
      int s = (j < rem) ? sv.x : 0;
      vv[j] = (j < rem) ? __int_as_float(sv.y) : 0.0f;
      g[j] = bf2f(hIn[(s << 6) + lane]);  // coalesced 128B row gather
    }
#pragma unroll
    for (int j = 0; j < 16; ++j) sum += vv[j] * g[j];
  }
  int idx = (node << 6) + lane;
  float a = __builtin_nontemporal_load(&acc[idx]);
  if (last) {
    __builtin_nontemporal_store((a + sum) * 0.25f, &acc[idx]);
  } else {
    __builtin_nontemporal_store(a + sum, &acc[idx]);
    __builtin_nontemporal_store(f2bf(jax_dropout(sum, k0, k1, (uint32_t)idx)),
                                &hOut[idx]);
  }
}

extern "C" void kernel_launch(void* const* d_in, const int* in_sizes, int n_in,
                              void* d_out, int out_size, void* d_ws, size_t ws_size,
                              hipStream_t stream) {
  const int* x = (const int*)d_in[0];
  const int* esrc = (const int*)d_in[1];
  const int* edst = (const int*)d_in[2];
  const float* evals = (const float*)d_in[3];
  const float* w = (const float*)d_in[4];
  float* acc = (float*)d_out;

  // ---- workspace layout (~26 MB) ----
  size_t nd = (size_t)kN * kD;
  int2* staged = (int2*)d_ws;                          // kE
  int2* csr_sv = staged + kE;                          // kE (+16 over-read slack)
  unsigned short* hB0 = (unsigned short*)(csr_sv + kE + 16);
  unsigned short* hB1 = hB0 + nd;
  int* locOffT = (int*)(hB1 + nd);                     // (kB+1)*kG
  int* bucketBase = locOffT + (kB + 1) * kG;           // kB+1
  int* offsets = bucketBase + kB + 1;                  // kN+1

  // JAX key derivation: key(1)=(0,1) -> split 3 (partitionable, verified R1).
  uint32_t dk[3][2];
  for (int i = 0; i < 3; ++i) tf2x32(0u, 1u, 0u, (uint32_t)i, &dk[i][0], &dk[i][1]);

  // 1) binA + init fused (independent work fills the GPU)
  fusedA_k<<<kG + kInitBlocks, 320, 0, stream>>>(esrc, edst, evals, locOffT, staged,
                                                 x, w, acc, hB0, dk[0][0], dk[0][1]);
  // 2) bucket size scan
  scanAll_k<<<1, 256, 0, stream>>>(locOffT, bucketBase, offsets);
  // 3) final CSR
  binB_k<<<kB, 256, 0, stream>>>(staged, locOffT, bucketBase, csr_sv, offsets);

  // 4) 3 layers, one wave per node
  const int gridL = (kN * kD) / 256;  // 12500 blocks
  layer_k<<<gridL, 256, 0, stream>>>(csr_sv, offsets, hB0, acc, hB1,
                                     dk[1][0], dk[1][1], 0);
  layer_k<<<gridL, 256, 0, stream>>>(csr_sv, offsets, hB1, acc, hB0,
                                     dk[2][0], dk[2][1], 0);
  layer_k<<<gridL, 256, 0, stream>>>(csr_sv, offsets, hB0, acc, hB1,
                                     0u, 0u, 1);
}

// Round 9
// 152.111 us; speedup vs baseline: 1.3667x; 1.0557x over previous
//
#include <hip/hip_runtime.h>
#include <stdint.h>

static const int kN = 50000;
static const int kD = 64;
static const int kE = 800000;
static const int kChunk = 3200;        // edges per binA block
static const int kG = kE / kChunk;     // 250 chunks (exact)
static const int kB = 196;             // buckets = node>>8 (256 nodes/bucket)
static const int kCapB = 6144;         // binB LDS edge cap (48KB)
static const int kInitBlocks = (kN * kD / 4 + 319) / 320;  // 2500

#define TFR(x0, x1, r)                                    \
  {                                                       \
    x0 += x1;                                             \
    x1 = ((x1 << (r)) | (x1 >> (32 - (r))));              \
    x1 ^= x0;                                             \
  }

// Threefry-2x32, 20 rounds, JAX key schedule (partitionable mode verified R1).
__host__ __device__ inline void tf2x32(uint32_t k0, uint32_t k1, uint32_t x0,
                                       uint32_t x1, uint32_t* o0, uint32_t* o1) {
  uint32_t k2 = k0 ^ k1 ^ 0x1BD11BDAu;
  x0 += k0; x1 += k1;
  TFR(x0, x1, 13) TFR(x0, x1, 15) TFR(x0, x1, 26) TFR(x0, x1, 6)
  x0 += k1; x1 += k2 + 1u;
  TFR(x0, x1, 17) TFR(x0, x1, 29) TFR(x0, x1, 16) TFR(x0, x1, 24)
  x0 += k2; x1 += k0 + 2u;
  TFR(x0, x1, 13) TFR(x0, x1, 15) TFR(x0, x1, 26) TFR(x0, x1, 6)
  x0 += k0; x1 += k1 + 3u;
  TFR(x0, x1, 17) TFR(x0, x1, 29) TFR(x0, x1, 16) TFR(x0, x1, 24)
  x0 += k1; x1 += k2 + 4u;
  TFR(x0, x1, 13) TFR(x0, x1, 15) TFR(x0, x1, 26) TFR(x0, x1, 6)
  x0 += k2; x1 += k0 + 5u;
  *o0 = x0; *o1 = x1;
}

__device__ inline float jax_dropout(float h, uint32_t k0, uint32_t k1, uint32_t idx) {
  uint32_t a, b;
  tf2x32(k0, k1, 0u, idx, &a, &b);
  uint32_t bits = a ^ b;
  float u = __uint_as_float((bits >> 9) | 0x3f800000u) - 1.0f;
  return (u < 0.9f) ? (h / 0.9f) : 0.0f;
}

__device__ inline unsigned short f2bf(float v) {  // RNE f32->bf16
  uint32_t x = __float_as_uint(v);
  return (unsigned short)((x + 0x7fffu + ((x >> 16) & 1u)) >> 16);
}
__device__ inline float bf2f(unsigned short b) {
  return __uint_as_float(((uint32_t)b) << 16);
}

// ------- fused: binA (LDS radix pass A) + init (embed + dropout) -------
__global__ __launch_bounds__(320) void fusedA_k(
    const int* __restrict__ esrc, const int* __restrict__ edst,
    const float* __restrict__ evals, int* __restrict__ locOffT,
    int2* __restrict__ staged, const int* __restrict__ x,
    const float* __restrict__ w, float* __restrict__ acc,
    unsigned short* __restrict__ hB, uint32_t k0, uint32_t k1) {
  int t = threadIdx.x;
  if (blockIdx.x < kG) {
    // ---- binA: per-chunk LDS sort by bucket, coalesced staging ----
    __shared__ int2 buf[kChunk];
    __shared__ int hist[kB];
    __shared__ int off[kB + 1];
    __shared__ int sm[2][256];
    int c = blockIdx.x;
    int base = c * kChunk;
    for (int i = t; i < kB; i += 320) hist[i] = 0;
    __syncthreads();
    int2 sv[10];
    int bkt[10];
#pragma unroll
    for (int i = 0; i < 10; ++i) {
      int e = base + t + i * 320;
      int d = edst[e];
      int b = d >> 8;
      bkt[i] = b;
      sv[i] = make_int2(((d & 255) << 16) | esrc[e], __float_as_int(evals[e]));
      atomicAdd(&hist[b], 1);
    }
    __syncthreads();
    int v = 0;
    if (t < 256) {
      v = (t < kB) ? hist[t] : 0;
      sm[0][t] = v;
    }
    __syncthreads();
    int p = 0;
    for (int o = 1; o < 256; o <<= 1) {
      if (t < 256) sm[p ^ 1][t] = sm[p][t] + ((t >= o) ? sm[p][t - o] : 0);
      __syncthreads();
      p ^= 1;
    }
    if (t < kB) off[t] = sm[p][t] - v;
    if (t == 0) off[kB] = kChunk;
    __syncthreads();
    for (int i = t; i <= kB; i += 320) locOffT[i * kG + c] = off[i];
    for (int i = t; i < kB; i += 320) hist[i] = off[i];  // cursors
    __syncthreads();
#pragma unroll
    for (int i = 0; i < 10; ++i) {
      int pos = atomicAdd(&hist[bkt[i]], 1);  // LDS atomic
      buf[pos] = sv[i];
    }
    __syncthreads();
    for (int i = t; i < kChunk; i += 320) staged[base + i] = buf[i];
  } else {
    // ---- init: acc = h0 (f32), hB = bf16(dropout(h0, dk1)) ----
    int gi = (blockIdx.x - kG) * 320 + t;  // one float4 per thread
    if (gi >= kN * kD / 4) return;
    int n = gi >> 4, d4 = gi & 15;
    float4 v = reinterpret_cast<const float4*>(w)[(size_t)x[n] * 16 + d4];
    reinterpret_cast<float4*>(acc)[gi] = v;
    uint32_t idx = (uint32_t)gi * 4u;
    ushort4 o;
    o.x = f2bf(jax_dropout(v.x, k0, k1, idx + 0));
    o.y = f2bf(jax_dropout(v.y, k0, k1, idx + 1));
    o.z = f2bf(jax_dropout(v.z, k0, k1, idx + 2));
    o.w = f2bf(jax_dropout(v.w, k0, k1, idx + 3));
    reinterpret_cast<ushort4*>(hB)[gi] = o;
  }
}

// Per-bucket column totals: colTot[b] = sum_c count(chunk c, bucket b).
// 196 blocks (one per bucket), tree reduce over the 250 chunks.
__global__ __launch_bounds__(256) void reduceB_k(const int* __restrict__ locOffT,
                                                 int* __restrict__ colTot) {
  __shared__ int red[256];
  int b = blockIdx.x, t = threadIdx.x;
  int v = 0;
  if (t < kG) v = locOffT[(b + 1) * kG + t] - locOffT[b * kG + t];
  red[t] = v;
  __syncthreads();
  for (int o = 128; o > 0; o >>= 1) {
    if (t < o) red[t] += red[t + o];
    __syncthreads();
  }
  if (t == 0) colTot[b] = red[0];
}

// Exclusive scan of the 196 bucket totals (1 block).
__global__ __launch_bounds__(256) void scanBB_k(const int* __restrict__ colTot,
                                                int* __restrict__ bucketBase,
                                                int* __restrict__ offsets) {
  __shared__ int sm[2][256];
  int t = threadIdx.x;
  int v = (t < kB) ? colTot[t] : 0;
  sm[0][t] = v;
  __syncthreads();
  int p = 0;
  for (int o = 1; o < 256; o <<= 1) {
    sm[p ^ 1][t] = sm[p][t] + ((t >= o) ? sm[p][t - o] : 0);
    __syncthreads();
    p ^= 1;
  }
  if (t < kB) bucketBase[t] = sm[p][t] - v;
  if (t == 0) {
    bucketBase[kB] = kE;
    offsets[kN] = kE;  // sentinel
  }
}

// Pass B (proven R5): one block per bucket; gather segments into LDS at known
// positions, node-histogram + scan -> offsets; LDS-cursor scatter to final CSR.
__global__ __launch_bounds__(256) void binB_k(const int2* __restrict__ staged,
                                              const int* __restrict__ locOffT,
                                              const int* __restrict__ bucketBase,
                                              int2* __restrict__ csr_sv,
                                              int* __restrict__ offsets) {
  __shared__ int2 buf[kCapB];
  __shared__ int sm[2][256];
  __shared__ int nodeA[256];  // cnt -> cursor
  int b = blockIdx.x, t = threadIdx.x;
  int base = bucketBase[b];
  int size = bucketBase[b + 1] - base;
  if (size > kCapB) size = kCapB;  // defensive (never hit for this graph)
  int myOff = 0, myCnt = 0;
  if (t < kG) {
    myOff = locOffT[b * kG + t];
    myCnt = locOffT[(b + 1) * kG + t] - myOff;
  }
  sm[0][t] = myCnt;
  __syncthreads();
  int p = 0;
  for (int o = 1; o < 256; o <<= 1) {
    sm[p ^ 1][t] = sm[p][t] + ((t >= o) ? sm[p][t - o] : 0);
    __syncthreads();
    p ^= 1;
  }
  int myPos = sm[p][t] - myCnt;  // chunk-major position within bucket
  for (int i = 0; i < myCnt; ++i) {
    int q = myPos + i;
    if (q < kCapB) buf[q] = staged[t * kChunk + myOff + i];
  }
  nodeA[t] = 0;
  __syncthreads();
  for (int i = t; i < size; i += 256) atomicAdd(&nodeA[buf[i].x >> 16], 1);
  __syncthreads();
  int nc = nodeA[t];
  sm[0][t] = nc;
  __syncthreads();
  p = 0;
  for (int o = 1; o < 256; o <<= 1) {
    sm[p ^ 1][t] = sm[p][t] + ((t >= o) ? sm[p][t - o] : 0);
    __syncthreads();
    p ^= 1;
  }
  int nOff = sm[p][t] - nc;
  int node = (b << 8) + t;
  if (node < kN) offsets[node] = base + nOff;
  nodeA[t] = nOff;  // becomes cursor
  __syncthreads();
  for (int i = t; i < size; i += 256) {
    int2 e = buf[i];
    int dl = e.x >> 16;
    int pp = atomicAdd(&nodeA[dl], 1);  // LDS atomic
    csr_sv[base + pp] = make_int2(e.x & 0xffff, e.y);
  }
}

// One wave per dst node; lane = dim. bf16 gathers (128B row = 1 line), f32
// accumulate; 16 gathers in flight to keep the miss queue full. acc/hOut
// traffic nontemporal.
__global__ __launch_bounds__(256) void layer_k(
    const int2* __restrict__ csr_sv, const int* __restrict__ offsets,
    const unsigned short* __restrict__ hIn, float* __restrict__ acc,
    unsigned short* __restrict__ hOut, uint32_t k0, uint32_t k1, int last) {
  int gtid = blockIdx.x * blockDim.x + threadIdx.x;
  int node = gtid >> 6;
  int lane = threadIdx.x & 63;
  if (node >= kN) return;
  int beg = __builtin_amdgcn_readfirstlane(offsets[node]);
  int end = __builtin_amdgcn_readfirstlane(offsets[node + 1]);
  int deg = end - beg;
  float sum = 0.0f;
  for (int c = 0; c < deg; c += 16) {
    const int2* p = csr_sv + beg + c;  // wave-uniform address -> scalar loads
    int rem = deg - c;
    float g[16], vv[16];
#pragma unroll
    for (int j = 0; j < 16; ++j) {
      int2 sv = p[j];  // over-read stays inside allocated ws; predicated off
      int s = (j < rem) ? sv.x : 0;
      vv[j] = (j < rem) ? __int_as_float(sv.y) : 0.0f;
      g[j] = bf2f(hIn[(s << 6) + lane]);  // coalesced 128B row gather
    }
#pragma unroll
    for (int j = 0; j < 16; ++j) sum += vv[j] * g[j];
  }
  int idx = (node << 6) + lane;
  float a = __builtin_nontemporal_load(&acc[idx]);
  if (last) {
    __builtin_nontemporal_store((a + sum) * 0.25f, &acc[idx]);
  } else {
    __builtin_nontemporal_store(a + sum, &acc[idx]);
    __builtin_nontemporal_store(f2bf(jax_dropout(sum, k0, k1, (uint32_t)idx)),
                                &hOut[idx]);
  }
}

extern "C" void kernel_launch(void* const* d_in, const int* in_sizes, int n_in,
                              void* d_out, int out_size, void* d_ws, size_t ws_size,
                              hipStream_t stream) {
  const int* x = (const int*)d_in[0];
  const int* esrc = (const int*)d_in[1];
  const int* edst = (const int*)d_in[2];
  const float* evals = (const float*)d_in[3];
  const float* w = (const float*)d_in[4];
  float* acc = (float*)d_out;

  // ---- workspace layout (~26 MB) ----
  size_t nd = (size_t)kN * kD;
  int2* staged = (int2*)d_ws;                          // kE
  int2* csr_sv = staged + kE;                          // kE (+16 over-read slack)
  unsigned short* hB0 = (unsigned short*)(csr_sv + kE + 16);
  unsigned short* hB1 = hB0 + nd;
  int* locOffT = (int*)(hB1 + nd);                     // (kB+1)*kG
  int* colTot = locOffT + (kB + 1) * kG;               // kB
  int* bucketBase = colTot + kB;                       // kB+1
  int* offsets = bucketBase + kB + 1;                  // kN+1

  // JAX key derivation: key(1)=(0,1) -> split 3 (partitionable, verified R1).
  uint32_t dk[3][2];
  for (int i = 0; i < 3; ++i) tf2x32(0u, 1u, 0u, (uint32_t)i, &dk[i][0], &dk[i][1]);

  // 1) binA + init fused (independent work fills the GPU)
  fusedA_k<<<kG + kInitBlocks, 320, 0, stream>>>(esrc, edst, evals, locOffT, staged,
                                                 x, w, acc, hB0, dk[0][0], dk[0][1]);
  // 2) per-bucket totals (parallel) + tiny exclusive scan
  reduceB_k<<<kB, 256, 0, stream>>>(locOffT, colTot);
  scanBB_k<<<1, 256, 0, stream>>>(colTot, bucketBase, offsets);
  // 3) final CSR
  binB_k<<<kB, 256, 0, stream>>>(staged, locOffT, bucketBase, csr_sv, offsets);

  // 4) 3 layers, one wave per node
  const int gridL = (kN * kD) / 256;  // 12500 blocks
  layer_k<<<gridL, 256, 0, stream>>>(csr_sv, offsets, hB0, acc, hB1,
                                     dk[1][0], dk[1][1], 0);
  layer_k<<<gridL, 256, 0, stream>>>(csr_sv, offsets, hB1, acc, hB0,
                                     dk[2][0], dk[2][1], 0);
  layer_k<<<gridL, 256, 0, stream>>>(csr_sv, offsets, hB0, acc, hB1,
                                     0u, 0u, 1);
}